// Round 1
// baseline (347.732 us; speedup 1.0000x reference)
//
#include <hip/hip_runtime.h>
#include <hip/hip_bf16.h>

// Fused MHA block: qkv proj -> flash attention -> out proj.
// All matmuls in bf16 MFMA (16x16x32), fp32 accumulate, fp32 softmax.
// Workspace layout (bytes):
//   [0,8M)   xb   : x cast to bf16           [4096][1024]
//   [8,14M)  wqb  : qkv_w bf16               [3072][1024]
//   [14,16M) pwb  : proj_w bf16              [1024][1024]
//   [16,24M) Qb   : Q*0.125 bf16 per head    [(b*16+h)*2048+n][64]
//   [24,32M) Kb   : K bf16 per head          [(b*16+h)*2048+n][64]
//   [32,40M) Vt   : V bf16 transposed        [(b*16+h)*64+hd][2048]
//   [40,48M) Ob   : attention out bf16       [b*2048+n][1024]

#define DEV __device__ __forceinline__

typedef __attribute__((ext_vector_type(8))) __bf16 bf16x8;
typedef __attribute__((ext_vector_type(4))) float f32x4;

static DEV unsigned short f2bf(float f) {
  unsigned u = __builtin_bit_cast(unsigned, f);
  u += 0x7FFFu + ((u >> 16) & 1u);   // round-to-nearest-even; inputs are finite
  return (unsigned short)(u >> 16);
}

static DEV void gld16(const void* g, void* l) {
  __builtin_amdgcn_global_load_lds(
      (const __attribute__((address_space(1))) unsigned int*)g,
      (__attribute__((address_space(3))) unsigned int*)l, 16, 0, 0);
}

static DEV f32x4 mfma16(bf16x8 a, bf16x8 b, f32x4 c) {
  return __builtin_amdgcn_mfma_f32_16x16x32_bf16(a, b, c, 0, 0, 0);
}

// ---------------- fp32 -> bf16 convert (exact-sized grid, 4 elem/thread) ----
__global__ void k_f2bf(const float* __restrict__ s, unsigned short* __restrict__ d) {
  int i = (blockIdx.x * 256 + threadIdx.x) * 4;
  float4 v = *reinterpret_cast<const float4*>(s + i);
  union { unsigned short h[4]; uint2 u; } cv;
  cv.h[0] = f2bf(v.x); cv.h[1] = f2bf(v.y); cv.h[2] = f2bf(v.z); cv.h[3] = f2bf(v.w);
  *reinterpret_cast<uint2*>(d + i) = cv.u;
}

// ---------------- QKV GEMM: C[4096][3072] = xb @ wqb^T + bias --------------
// 128x128 tile, BK=32, 4 waves (2x2), each wave 64x64 = 4x4 fragments.
__global__ __launch_bounds__(256) void k_qkv(
    const unsigned short* __restrict__ A, const unsigned short* __restrict__ W,
    const float* __restrict__ bias, unsigned short* __restrict__ Qb,
    unsigned short* __restrict__ Kb, unsigned short* __restrict__ Vt) {
  const int K = 1024;
  __shared__ __align__(16) unsigned short As[128 * 32], Bs[128 * 32];
  const int tid = threadIdx.x, lane = tid & 63, wid = tid >> 6;
  const int wm = wid >> 1, wn = wid & 1, fr = lane & 15, fg = lane >> 4;
  const size_t bm = blockIdx.x, bn = blockIdx.y;
  const unsigned short* gA = A + bm * 128 * K;
  const unsigned short* gW = W + bn * 128 * K;
  f32x4 acc[4][4] = {};
  for (int k0 = 0; k0 < K; k0 += 32) {
#pragma unroll
    for (int c = 0; c < 2; ++c) {
      int bi = c * 4096 + wid * 1024 + lane * 16;  // byte index within 8KB tile
      int row = bi >> 6, ce = (bi & 63) >> 1;      // ce = element offset in row
      gld16(gA + (size_t)row * K + k0 + ce, As + c * 2048 + wid * 512);
      gld16(gW + (size_t)row * K + k0 + ce, Bs + c * 2048 + wid * 512);
    }
    __syncthreads();
    bf16x8 af[4], bw[4];
#pragma unroll
    for (int m = 0; m < 4; ++m)
      af[m] = *reinterpret_cast<const bf16x8*>(As + (wm * 64 + m * 16 + fr) * 32 + fg * 8);
#pragma unroll
    for (int n = 0; n < 4; ++n)
      bw[n] = *reinterpret_cast<const bf16x8*>(Bs + (wn * 64 + n * 16 + fr) * 32 + fg * 8);
#pragma unroll
    for (int m = 0; m < 4; ++m)
#pragma unroll
      for (int n = 0; n < 4; ++n)
        acc[m][n] = mfma16(af[m], bw[n], acc[m][n]);
    __syncthreads();
  }
  float bv[4];
#pragma unroll
  for (int n = 0; n < 4; ++n) bv[n] = bias[bn * 128 + wn * 64 + n * 16 + fr];
#pragma unroll
  for (int m = 0; m < 4; ++m)
#pragma unroll
    for (int n = 0; n < 4; ++n)
#pragma unroll
      for (int r = 0; r < 4; ++r) {
        int row = wm * 64 + m * 16 + fg * 4 + r;
        int token = (int)bm * 128 + row;
        int b_ = token >> 11, nn = token & 2047;
        int f = (int)bn * 128 + wn * 64 + n * 16 + fr;
        float val = acc[m][n][r] + bv[n];
        int t = f >> 10, d = f & 1023, h = d >> 6, hd = d & 63;
        size_t bh = (size_t)(b_ * 16 + h);
        if (t == 0)      Qb[(bh * 2048 + nn) * 64 + hd] = f2bf(val * 0.125f);
        else if (t == 1) Kb[(bh * 2048 + nn) * 64 + hd] = f2bf(val);
        else             Vt[(bh * 64 + hd) * 2048 + nn] = f2bf(val);
      }
}

// ---------------- Flash attention -----------------------------------------
// grid 512 = (b,h) * 16 q-tiles of 128; 4 waves x 32 q-rows; KV tile 64.
__global__ __launch_bounds__(256) void k_attn(
    const unsigned short* __restrict__ Qb, const unsigned short* __restrict__ Kb,
    const unsigned short* __restrict__ Vt, unsigned short* __restrict__ Ob) {
  __shared__ __align__(16) unsigned short p_lds[4][32][72];  // wave-private P
  const int tid = threadIdx.x, lane = tid & 63, w = tid >> 6;
  const int fr = lane & 15, fg = lane >> 4;
  const int qt = blockIdx.x & 15, bh = blockIdx.x >> 4;
  const unsigned short* Qp = Qb + ((size_t)bh * 2048 + qt * 128 + w * 32) * 64;
  const unsigned short* Kp = Kb + (size_t)bh * 2048 * 64;
  const unsigned short* Vp = Vt + (size_t)bh * 64 * 2048;
  bf16x8 qf[2][2];
#pragma unroll
  for (int m = 0; m < 2; ++m)
#pragma unroll
    for (int ks = 0; ks < 2; ++ks)
      qf[m][ks] = *reinterpret_cast<const bf16x8*>(Qp + (m * 16 + fr) * 64 + ks * 32 + fg * 8);
  f32x4 accO[2][4] = {};
  float mrun[2][4], lrun[2][4];
#pragma unroll
  for (int m = 0; m < 2; ++m)
#pragma unroll
    for (int r = 0; r < 4; ++r) { mrun[m][r] = -INFINITY; lrun[m][r] = 0.f; }

  for (int kt = 0; kt < 32; ++kt) {
    const unsigned short* Kt = Kp + kt * 64 * 64;
    f32x4 s[2][4] = {};
#pragma unroll
    for (int nf = 0; nf < 4; ++nf)
#pragma unroll
      for (int ks = 0; ks < 2; ++ks) {
        bf16x8 kf = *reinterpret_cast<const bf16x8*>(Kt + (nf * 16 + fr) * 64 + ks * 32 + fg * 8);
        s[0][nf] = mfma16(qf[0][ks], kf, s[0][nf]);
        s[1][nf] = mfma16(qf[1][ks], kf, s[1][nf]);
      }
    // online softmax (rows owned per lane: q = m*16 + fg*4 + r; cols across 16 lanes)
#pragma unroll
    for (int m = 0; m < 2; ++m)
#pragma unroll
      for (int r = 0; r < 4; ++r) {
        float v = fmaxf(fmaxf(s[m][0][r], s[m][1][r]), fmaxf(s[m][2][r], s[m][3][r]));
        v = fmaxf(v, __shfl_xor(v, 1));
        v = fmaxf(v, __shfl_xor(v, 2));
        v = fmaxf(v, __shfl_xor(v, 4));
        v = fmaxf(v, __shfl_xor(v, 8));
        float mnew = fmaxf(mrun[m][r], v);
        float sc = __expf(mrun[m][r] - mnew);
        mrun[m][r] = mnew;
        float rs = 0.f;
#pragma unroll
        for (int nf = 0; nf < 4; ++nf) {
          float p = __expf(s[m][nf][r] - mnew);
          s[m][nf][r] = p;
          rs += p;
        }
        rs += __shfl_xor(rs, 1);
        rs += __shfl_xor(rs, 2);
        rs += __shfl_xor(rs, 4);
        rs += __shfl_xor(rs, 8);
        lrun[m][r] = lrun[m][r] * sc + rs;
#pragma unroll
        for (int df = 0; df < 4; ++df) accO[m][df][r] *= sc;
      }
    // P -> LDS (C-layout scalar writes), read back as A-fragments (vector).
    // Region is wave-private: no __syncthreads needed, lgkmcnt ordering only.
#pragma unroll
    for (int m = 0; m < 2; ++m)
#pragma unroll
      for (int nf = 0; nf < 4; ++nf)
#pragma unroll
        for (int r = 0; r < 4; ++r)
          p_lds[w][m * 16 + fg * 4 + r][nf * 16 + fr] = f2bf(s[m][nf][r]);
#pragma unroll
    for (int ks = 0; ks < 2; ++ks) {
      bf16x8 pf0 = *reinterpret_cast<const bf16x8*>(&p_lds[w][fr][ks * 32 + fg * 8]);
      bf16x8 pf1 = *reinterpret_cast<const bf16x8*>(&p_lds[w][16 + fr][ks * 32 + fg * 8]);
#pragma unroll
      for (int df = 0; df < 4; ++df) {
        bf16x8 vf = *reinterpret_cast<const bf16x8*>(
            Vp + (size_t)(df * 16 + fr) * 2048 + kt * 64 + ks * 32 + fg * 8);
        accO[0][df] = mfma16(pf0, vf, accO[0][df]);
        accO[1][df] = mfma16(pf1, vf, accO[1][df]);
      }
    }
  }
  const int b_ = bh >> 4, h = bh & 15;
#pragma unroll
  for (int m = 0; m < 2; ++m)
#pragma unroll
    for (int df = 0; df < 4; ++df)
#pragma unroll
      for (int r = 0; r < 4; ++r) {
        int nn = qt * 128 + w * 32 + m * 16 + fg * 4 + r;
        int d = df * 16 + fr;
        float o = accO[m][df][r] / lrun[m][r];
        Ob[(size_t)(b_ * 2048 + nn) * 1024 + h * 64 + d] = f2bf(o);
      }
}

// ---------------- Proj GEMM: out[4096][1024] = Ob @ pwb^T + bias (fp32 out) -
__global__ __launch_bounds__(256) void k_proj(
    const unsigned short* __restrict__ A, const unsigned short* __restrict__ W,
    const float* __restrict__ bias, float* __restrict__ out) {
  const int K = 1024;
  __shared__ __align__(16) unsigned short As[128 * 32], Bs[128 * 32];
  const int tid = threadIdx.x, lane = tid & 63, wid = tid >> 6;
  const int wm = wid >> 1, wn = wid & 1, fr = lane & 15, fg = lane >> 4;
  const size_t bm = blockIdx.x, bn = blockIdx.y;
  const unsigned short* gA = A + bm * 128 * K;
  const unsigned short* gW = W + bn * 128 * K;
  f32x4 acc[4][4] = {};
  for (int k0 = 0; k0 < K; k0 += 32) {
#pragma unroll
    for (int c = 0; c < 2; ++c) {
      int bi = c * 4096 + wid * 1024 + lane * 16;
      int row = bi >> 6, ce = (bi & 63) >> 1;
      gld16(gA + (size_t)row * K + k0 + ce, As + c * 2048 + wid * 512);
      gld16(gW + (size_t)row * K + k0 + ce, Bs + c * 2048 + wid * 512);
    }
    __syncthreads();
    bf16x8 af[4], bw[4];
#pragma unroll
    for (int m = 0; m < 4; ++m)
      af[m] = *reinterpret_cast<const bf16x8*>(As + (wm * 64 + m * 16 + fr) * 32 + fg * 8);
#pragma unroll
    for (int n = 0; n < 4; ++n)
      bw[n] = *reinterpret_cast<const bf16x8*>(Bs + (wn * 64 + n * 16 + fr) * 32 + fg * 8);
#pragma unroll
    for (int m = 0; m < 4; ++m)
#pragma unroll
      for (int n = 0; n < 4; ++n)
        acc[m][n] = mfma16(af[m], bw[n], acc[m][n]);
    __syncthreads();
  }
  float bv[4];
#pragma unroll
  for (int n = 0; n < 4; ++n) bv[n] = bias[bn * 128 + wn * 64 + n * 16 + fr];
#pragma unroll
  for (int m = 0; m < 4; ++m)
#pragma unroll
    for (int n = 0; n < 4; ++n)
#pragma unroll
      for (int r = 0; r < 4; ++r) {
        size_t token = bm * 128 + wm * 64 + m * 16 + fg * 4 + r;
        int f = (int)bn * 128 + wn * 64 + n * 16 + fr;
        out[token * 1024 + f] = acc[m][n][r] + bv[n];
      }
}

extern "C" void kernel_launch(void* const* d_in, const int* in_sizes, int n_in,
                              void* d_out, int out_size, void* d_ws, size_t ws_size,
                              hipStream_t stream) {
  const float* x      = (const float*)d_in[0];
  const float* qkv_w  = (const float*)d_in[1];
  const float* qkv_b  = (const float*)d_in[2];
  const float* proj_w = (const float*)d_in[3];
  const float* proj_b = (const float*)d_in[4];
  float* out = (float*)d_out;
  char* ws = (char*)d_ws;
  unsigned short* xb  = (unsigned short*)(ws);
  unsigned short* wqb = (unsigned short*)(ws + (size_t)(8u << 20));
  unsigned short* pwb = (unsigned short*)(ws + (size_t)(14u << 20));
  unsigned short* Qb  = (unsigned short*)(ws + (size_t)(16u << 20));
  unsigned short* Kb  = (unsigned short*)(ws + (size_t)(24u << 20));
  unsigned short* Vt  = (unsigned short*)(ws + (size_t)(32u << 20));
  unsigned short* Ob  = (unsigned short*)(ws + (size_t)(40u << 20));

  k_f2bf<<<4096, 256, 0, stream>>>(x, xb);        // 4096*1024   elems
  k_f2bf<<<3072, 256, 0, stream>>>(qkv_w, wqb);   // 3072*1024
  k_f2bf<<<1024, 256, 0, stream>>>(proj_w, pwb);  // 1024*1024
  k_qkv<<<dim3(32, 24), 256, 0, stream>>>(xb, wqb, qkv_b, Qb, Kb, Vt);
  k_attn<<<512, 256, 0, stream>>>(Qb, Kb, Vt, Ob);
  k_proj<<<dim3(32, 8), 256, 0, stream>>>(Ob, pwb, proj_b, out);
}